// Round 11
// baseline (671.007 us; speedup 1.0000x reference)
//
#include <hip/hip_runtime.h>
#include <hip/hip_bf16.h>

typedef __hip_bfloat16 bf16;
typedef unsigned short u16;
typedef unsigned int   u32;

constexpr int Hn=64, Wn=64, Cm=96, Ln=4096, Di=192, Kn=4, Ns=16, Rr=6;
constexpr int Gc=64, CH=64;   // 64 chunks of 64 positions

typedef __attribute__((ext_vector_type(8))) short bf16x8;
typedef __attribute__((ext_vector_type(4))) float f32x4;

static __device__ __forceinline__ float ldv(const float* p, long i){ return p[i]; }
static __device__ __forceinline__ float ldv(const bf16*  p, long i){ return __bfloat162float(p[i]); }
static __device__ __forceinline__ void  stv(float* p, long i, float v){ p[i] = v; }
static __device__ __forceinline__ void  stv(bf16*  p, long i, float v){ p[i] = __float2bfloat16(v); }
static __device__ __forceinline__ float bfr(u16 u){ return __uint_as_float((u32)u << 16); }
static __device__ __forceinline__ u16   fbr(float f){ bf16 h = __float2bfloat16(f); return *(u16*)&h; }
static __device__ __forceinline__ float4 ldv4(const float* p, long i){ return *(const float4*)(p + i); }
static __device__ __forceinline__ float4 ldv4(const bf16* p, long i){
  ushort4 u = *(const ushort4*)(p + i);
  return make_float4(bfr(u.x), bfr(u.y), bfr(u.z), bfr(u.w));
}
static __device__ __forceinline__ float splus(float x){ return (x > 15.f) ? x : log1pf(__expf(x)); }

// load 8 contiguous elems as a bf16 MFMA fragment (convert if f32)
static __device__ __forceinline__ bf16x8 ldb8(const float* p){
  float4 a = *(const float4*)p;
  float4 b = *(const float4*)(p + 4);
  bf16x8 r;
  r[0]=(short)fbr(a.x); r[1]=(short)fbr(a.y); r[2]=(short)fbr(a.z); r[3]=(short)fbr(a.w);
  r[4]=(short)fbr(b.x); r[5]=(short)fbr(b.y); r[6]=(short)fbr(b.z); r[7]=(short)fbr(b.w);
  return r;
}
static __device__ __forceinline__ bf16x8 ldb8(const bf16* p){
  return *(const bf16x8*)p;
}
// store 8 elems into LDS as bf16 (convert if f32)
static __device__ __forceinline__ void st8(u16* dst, const float* src){
  float4 a = *(const float4*)src;
  float4 b = *(const float4*)(src + 4);
  dst[0]=fbr(a.x); dst[1]=fbr(a.y); dst[2]=fbr(a.z); dst[3]=fbr(a.w);
  dst[4]=fbr(b.x); dst[5]=fbr(b.y); dst[6]=fbr(b.z); dst[7]=fbr(b.w);
}
static __device__ __forceinline__ void st8(u16* dst, const bf16* src){
  *(ushort4*)dst       = *(const ushort4*)src;
  *(ushort4*)(dst + 4) = *(const ushort4*)(src + 4);
}

// ---------------- dtype detector (f32 vs bf16) + Alog structure detector
__global__ void k_detect(const u16* x, const void* Alog, int* flag, int* flag2){
  __shared__ int cnt, cnt2;
  if (threadIdx.x == 0){ cnt = 0; cnt2 = 0; }
  __syncthreads();
  int local = 0;
  for (int i = threadIdx.x; i < 8192; i += 256){
    int e = (x[i] >> 7) & 0xFF;
    if (e != 0 && (e < 90 || e > 164)) local++;
  }
  atomicAdd(&cnt, local);
  __syncthreads();
  int f = (cnt > 400) ? 1 : 0;          // 1 => float32 inputs
  int bad = 0;
  for (int i = threadIdx.x; i < Di*Ns; i += 256){
    float v = f ? ((const float*)Alog)[i] : bfr(((const u16*)Alog)[i]);
    float ex = __logf((float)((i & 15) + 1));
    if (fabsf(v - ex) > 1e-5f) bad++;
  }
  atomicAdd(&cnt2, bad);
  __syncthreads();
  if (threadIdx.x == 0){ *flag = f; *flag2 = (cnt2 == 0) ? 1 : 0; }
}

// ---------------------------------------------------------------- in_proj GEMM (MFMA)
template<typename T>
__device__ void inproj_body(const T* x, const T* w, u16* Xb, u16* Z, u16* sA, u16* sC){
  int tid = threadIdx.x;
  long p0 = (long)blockIdx.x * 64;
  for (int i = tid; i < 768; i += 256){
    int r = i / 12, c = (i % 12) * 8;
    st8(&sA[r*104 + c], x + p0*96 + (long)r*96 + c);
  }
  __syncthreads();
  int wid = tid >> 6, lane = tid & 63;
  int lr = lane & 15, lh = lane >> 4;
  int colbase = wid * 96;
  f32x4 acc[4][6] = {};
  #pragma unroll
  for (int ks = 0; ks < 3; ++ks){
    int k0 = ks*32 + lh*8;
    bf16x8 af[4];
    #pragma unroll
    for (int m = 0; m < 4; ++m)
      af[m] = *(const bf16x8*)&sA[(m*16 + lr)*104 + k0];
    #pragma unroll
    for (int n = 0; n < 6; ++n){
      bf16x8 b8 = ldb8(w + (long)(colbase + n*16 + lr)*96 + k0);
      #pragma unroll
      for (int m = 0; m < 4; ++m)
        acc[m][n] = __builtin_amdgcn_mfma_f32_16x16x32_bf16(af[m], b8, acc[m][n], 0, 0, 0);
    }
  }
  #pragma unroll
  for (int n = 0; n < 6; ++n){
    int gc = colbase + n*16 + lr;
    #pragma unroll
    for (int m = 0; m < 4; ++m){
      #pragma unroll
      for (int r = 0; r < 4; ++r)
        sC[(m*16 + lh*4 + r)*392 + gc] = fbr(acc[m][n][r]);
    }
  }
  __syncthreads();
  for (int i = tid; i < 3072; i += 256){
    int r = i / 48, c = (i % 48) * 8;
    ushort4 v0 = *(const ushort4*)&sC[r*392 + c];
    ushort4 v1 = *(const ushort4*)&sC[r*392 + c + 4];
    u16* dst = (c < 192) ? (Xb + (p0 + r)*192 + c) : (Z + (p0 + r)*192 + (c - 192));
    *(ushort4*)dst       = v0;
    *(ushort4*)(dst + 4) = v1;
  }
}
__global__ __launch_bounds__(256) void k_inproj(const void* x, long xoff, const void* w,
                                                u16* Xb, u16* Z, const int* flag){
  __shared__ u16 sA[64*104];
  __shared__ u16 sC[64*392];
  if (*flag) inproj_body<float>((const float*)x + xoff, (const float*)w, Xb, Z, sA, sC);
  else       inproj_body<bf16 >((const bf16* )x + xoff, (const bf16* )w, Xb, Z, sA, sC);
}

// ------------------- depthwise conv3x3 + SiLU -> xcLD (L,D) and xcTLD (Lt,D)
template<typename T>
__device__ void conv_body(const u16* Xb, const T* cw, const T* cb,
                          u16* xcLD, u16* xcTLD, float* wv, float* bv){
  int blk = blockIdx.x;
  int dq = blk % 3; int hb = blk / 3; int h = hb & 63; int b = hb >> 6;
  int tid = threadIdx.x;
  int d0 = dq*64;
  for (int i = tid; i < 576; i += 256){
    int c = i & 63, t = i >> 6;
    wv[t*64 + c] = ldv(cw, (long)(d0 + c)*9 + t);
  }
  if (tid < 64) bv[tid] = ldv(cb, d0 + tid);
  __syncthreads();
  const u16* Xbb = Xb + (long)b*Ln*Di;
  u16* xa = xcLD  + (long)b*Ln*Di;
  u16* xb = xcTLD + (long)b*Ln*Di;
  int c8l = (tid & 7)*8;
  int d = d0 + c8l;
  float4 wf[9][2];
  #pragma unroll
  for (int t = 0; t < 9; ++t){
    wf[t][0] = *(const float4*)&wv[t*64 + c8l];
    wf[t][1] = *(const float4*)&wv[t*64 + c8l + 4];
  }
  float bss[8];
  #pragma unroll
  for (int q = 0; q < 8; ++q) bss[q] = bv[c8l + q];
  #pragma unroll
  for (int half = 0; half < 2; ++half){
    int w = (tid >> 3) + half*32;
    float acc[8];
    #pragma unroll
    for (int q = 0; q < 8; ++q) acc[q] = bss[q];
    #pragma unroll
    for (int dh = -1; dh <= 1; ++dh){
      int hh = h + dh;
      if ((unsigned)hh > 63u) continue;
      #pragma unroll
      for (int dw = -1; dw <= 1; ++dw){
        int ww = w + dw;
        if ((unsigned)ww > 63u) continue;
        int t = (dh+1)*3 + (dw+1);
        const u16* p = Xbb + (long)(hh*64 + ww)*Di + d;
        ushort4 v0 = *(const ushort4*)p;
        ushort4 v1 = *(const ushort4*)(p + 4);
        acc[0] += wf[t][0].x * bfr(v0.x);
        acc[1] += wf[t][0].y * bfr(v0.y);
        acc[2] += wf[t][0].z * bfr(v0.z);
        acc[3] += wf[t][0].w * bfr(v0.w);
        acc[4] += wf[t][1].x * bfr(v1.x);
        acc[5] += wf[t][1].y * bfr(v1.y);
        acc[6] += wf[t][1].z * bfr(v1.z);
        acc[7] += wf[t][1].w * bfr(v1.w);
      }
    }
    u16 o[8];
    #pragma unroll
    for (int q = 0; q < 8; ++q){
      float e = __expf(-acc[q]);
      float sv = acc[q] * __builtin_amdgcn_rcpf(1.f + e);
      o[q] = fbr(sv);
    }
    ushort4 s0; s0.x=o[0]; s0.y=o[1]; s0.z=o[2]; s0.w=o[3];
    ushort4 s1; s1.x=o[4]; s1.y=o[5]; s1.z=o[6]; s1.w=o[7];
    u16* pa = xa + (long)(h*64 + w)*Di + d;
    u16* pb = xb + (long)(w*64 + h)*Di + d;
    *(ushort4*)pa = s0; *(ushort4*)(pa + 4) = s1;
    *(ushort4*)pb = s0; *(ushort4*)(pb + 4) = s1;
  }
}
__global__ __launch_bounds__(256,4) void k_conv(const u16* Xb, const void* cw, const void* cb,
                                                u16* xcLD, u16* xcTLD, const int* flag){
  __shared__ float wv[576];
  __shared__ float bv[64];
  if (*flag) conv_body<float>(Xb, (const float*)cw, (const float*)cb, xcLD, xcTLD, wv, bv);
  else       conv_body<bf16 >(Xb, (const bf16* )cw, (const bf16* )cb, xcLD, xcTLD, wv, bv);
}

// --------------------------------------------- x_proj (MFMA): dts + packed B/C, scan order
template<typename T>
__device__ void proj_body(const u16* xcLD, const u16* xcTLD, const T* xpw,
                          u16* dtsg, u32* BCg, u16* sA){
  int tid = threadIdx.x;
  int s = blockIdx.x & 1;
  long q0 = (long)(blockIdx.x >> 1) * 64;
  const u16* src = (s ? xcTLD : xcLD) + q0*192;
  for (int i = tid; i < 1536; i += 256){
    int r = i / 24, c = (i % 24) * 8;
    const u16* sp = src + (long)r*192 + c;
    *(ushort4*)&sA[r*200 + c]     = *(const ushort4*)sp;
    *(ushort4*)&sA[r*200 + c + 4] = *(const ushort4*)(sp + 4);
  }
  __syncthreads();
  int wid = tid >> 6, lane = tid & 63;
  int lr = lane & 15, lh = lane >> 4;
  f32x4 acc[5] = {};
  #pragma unroll
  for (int ks = 0; ks < 6; ++ks){
    int k0 = ks*32 + lh*8;
    bf16x8 a = *(const bf16x8*)&sA[(wid*16 + lr)*200 + k0];
    #pragma unroll
    for (int f = 0; f < 5; ++f){
      int c = f*16 + lr;
      int cw;
      if (c < 38)      cw = s*38 + c;
      else if (c < 76) cw = (s+2)*38 + (c - 38);
      else             cw = 0;
      bf16x8 b8 = ldb8(xpw + (long)cw*192 + k0);
      acc[f] = __builtin_amdgcn_mfma_f32_16x16x32_bf16(a, b8, acc[f], 0, 0, 0);
    }
  }
  int row_l = wid*16 + lh*4;
  #pragma unroll
  for (int f = 0; f < 5; ++f){
    int c = f*16 + lr;
    if (c >= 76) continue;
    int k = (c < 38) ? s : s + 2;
    int t = (c < 38) ? c : c - 38;
    if (t >= 22) continue;
    #pragma unroll
    for (int r = 0; r < 4; ++r){
      long q = q0 + row_l + r;
      int b  = (int)(q >> 12);
      int ql = (int)(q & 4095);
      int l  = (k >= 2) ? (4095 - ql) : ql;
      long base = ((long)(b*4 + k))*4096 + l;
      if (t < 6){
        dtsg[base*6 + t] = fbr(acc[f][r]);
      } else {
        int n = t - 6;
        u32 v = (u32)fbr(acc[f][r]) | ((u32)fbr(acc[f+1][r]) << 16);
        BCg[base*16 + n] = v;
      }
    }
  }
}
__global__ __launch_bounds__(256) void k_proj(const u16* xcLD, const u16* xcTLD, const void* xpw,
                                              u16* dtsg, u32* BCg, const int* flag){
  __shared__ u16 sA[64*200];
  if (*flag) proj_body<float>(xcLD, xcTLD, (const float*)xpw, dtsg, BCg, sA);
  else       proj_body<bf16 >(xcLD, xcTLD, (const bf16* )xpw, dtsg, BCg, sA);
}

// softplus + decay pair: dl = softplus(xv), rr = exp(-dl) (reuses exp(xv))
static __device__ __forceinline__ void sp_decay(float xv, float& dl, float& rr){
  if (xv > 15.f){ dl = xv; rr = __expf(-xv); }
  else {
    float o = 1.f + __expf(xv);
    dl = __logf(o);
    rr = __builtin_amdgcn_rcpf(o);
  }
}

// ======================= SCAN PASS 1 =======================
// Proven structure (see ledger in previous rounds). Round-11 experiment:
// u-load batch depth 8 -> 16 (uv lives within ONE iteration, NOT loop-carried
// — distinct from r6's failed cross-iteration prefetch). Buries the per-batch
// vmcnt stall under 2x compute; VGPR 36 -> ~55, safely under the 64 cliff.
__global__ __launch_bounds__(192,3) void k_scan1_fast(const u16* xcLD, const u16* xcTLD,
                                                      const u16* dtsg, const u32* BCg,
                                                      const void* dtw, const void* dtb,
                                                      float* Sb, float* Qb,
                                                      const int* flag, const int* flag2){
  if (!(*flag && *flag2)) return;
  __shared__ float sdt[384];
  __shared__ float sB[1024];
  const float* dtwf = (const float*)dtw;
  const float* dtbf = (const float*)dtb;
  int tid = threadIdx.x, blk = blockIdx.x;
  int g = blk & (Gc-1); int k = (blk >> 6) & 3; int b = blk >> 8;
  bool rev = k >= 2, odd = k & 1;
  int d = tid;
  const u16* src = (odd ? xcTLD : xcLD) + (long)b*Ln*Di;
  const u16* dlg = dtsg + (long)(b*Kn + k)*Ln*6;
  const u32* bcg = BCg + (long)(b*Kn + k)*Ln*16;
  float w[6], h[16];
  #pragma unroll
  for (int r = 0; r < 6; ++r) w[r] = dtwf[((long)k*Di + d)*6 + r];
  float bias = dtbf[k*Di + d];
  #pragma unroll
  for (int n = 0; n < 16; ++n) h[n] = 0.f;
  float S = 0.f;
  int l0 = g*CH;
  for (int i = tid; i < 48; i += 192){
    const u16* sp8 = dlg + (long)l0*6 + i*8;
    ushort4 v0 = *(const ushort4*)sp8;
    ushort4 v1 = *(const ushort4*)(sp8 + 4);
    float* dp = &sdt[i*8];
    dp[0]=bfr(v0.x); dp[1]=bfr(v0.y); dp[2]=bfr(v0.z); dp[3]=bfr(v0.w);
    dp[4]=bfr(v1.x); dp[5]=bfr(v1.y); dp[6]=bfr(v1.z); dp[7]=bfr(v1.w);
  }
  for (int i = tid; i < 256; i += 192){
    uint4 v = *(const uint4*)(bcg + (long)l0*16 + i*4);
    sB[i*4+0] = bfr((u16)(v.x & 0xffff));
    sB[i*4+1] = bfr((u16)(v.y & 0xffff));
    sB[i*4+2] = bfr((u16)(v.z & 0xffff));
    sB[i*4+3] = bfr((u16)(v.w & 0xffff));
  }
  __syncthreads();
  for (int jb = 0; jb < CH; jb += 16){
    float uv[16];
    #pragma unroll
    for (int q = 0; q < 16; ++q){
      int l = l0 + jb + q; int pos = rev ? (Ln-1-l) : l;
      uv[q] = bfr(src[(long)pos*Di + d]);
    }
    #pragma unroll
    for (int q = 0; q < 16; ++q){
      int j = jb + q;
      float xv = bias;
      #pragma unroll
      for (int r = 0; r < 6; ++r) xv += w[r]*sdt[j*6 + r];
      float dl, rr; sp_decay(xv, dl, rr);
      float du = dl * uv[q];
      float Bv[16];
      *(float4*)&Bv[0]  = *(const float4*)&sB[j*16];
      *(float4*)&Bv[4]  = *(const float4*)&sB[j*16+4];
      *(float4*)&Bv[8]  = *(const float4*)&sB[j*16+8];
      *(float4*)&Bv[12] = *(const float4*)&sB[j*16+12];
      float r2 = rr*rr, r3 = r2*rr, r4 = r2*r2, r8 = r4*r4, r12 = r8*r4;
      float S4[4] = {rr, r2, r3, r4};
      float B4[4] = {1.f, r4, r8, r12};
      #pragma unroll
      for (int n = 0; n < 16; ++n)
        h[n] = (B4[n>>2]*S4[n&3])*h[n] + du*Bv[n];
      S += dl;
    }
  }
  long ci = (long)(b*Kn + k)*Gc + g;
  Sb[ci*Di + d] = S;
  float4* qp = (float4*)(Qb + ci*3072 + (long)d*16);
  qp[0] = make_float4(h[0], h[1], h[2], h[3]);
  qp[1] = make_float4(h[4], h[5], h[6], h[7]);
  qp[2] = make_float4(h[8], h[9], h[10], h[11]);
  qp[3] = make_float4(h[12], h[13], h[14], h[15]);
}

// general fallback (bf16 dtype or non-structured Alog) — early-exits when fast ran
template<typename T>
__device__ void scan1_body(const u16* xcLD, const u16* xcTLD, const u16* dtsg, const u32* BCg,
                           const T* Alog, const T* dtw, const T* dtb,
                           float* Sb, float* Qb, float* sdt, float* sB, int fastA){
  int tid = threadIdx.x, blk = blockIdx.x;
  int g = blk & (Gc-1); int k = (blk >> 6) & 3; int b = blk >> 8;
  bool rev = k >= 2, odd = k & 1;
  int d = tid;
  const u16* src = (odd ? xcTLD : xcLD) + (long)b*Ln*Di;
  const u16* dlg = dtsg + (long)(b*Kn + k)*Ln*6;
  const u32* bcg = BCg + (long)(b*Kn + k)*Ln*16;
  float w[6], h[16], a[16];
  #pragma unroll
  for (int r = 0; r < 6; ++r) w[r] = ldv(dtw, ((long)k*Di + d)*6 + r);
  float bias = ldv(dtb, k*Di + d);
  #pragma unroll
  for (int n = 0; n < 16; ++n) h[n] = 0.f;
  if (!fastA){
    #pragma unroll
    for (int n = 0; n < 16; ++n) a[n] = -__expf(ldv(Alog, (long)d*16 + n));
  }
  float S = 0.f;
  int l0 = g*CH;
  for (int i = tid; i < 48; i += 192){
    const u16* sp8 = dlg + (long)l0*6 + i*8;
    ushort4 v0 = *(const ushort4*)sp8;
    ushort4 v1 = *(const ushort4*)(sp8 + 4);
    float* dp = &sdt[i*8];
    dp[0]=bfr(v0.x); dp[1]=bfr(v0.y); dp[2]=bfr(v0.z); dp[3]=bfr(v0.w);
    dp[4]=bfr(v1.x); dp[5]=bfr(v1.y); dp[6]=bfr(v1.z); dp[7]=bfr(v1.w);
  }
  for (int i = tid; i < 256; i += 192){
    uint4 v = *(const uint4*)(bcg + (long)l0*16 + i*4);
    sB[i*4+0] = bfr((u16)(v.x & 0xffff));
    sB[i*4+1] = bfr((u16)(v.y & 0xffff));
    sB[i*4+2] = bfr((u16)(v.z & 0xffff));
    sB[i*4+3] = bfr((u16)(v.w & 0xffff));
  }
  __syncthreads();
  if (fastA){
    for (int jb = 0; jb < CH; jb += 8){
      float uv[8];
      #pragma unroll
      for (int q = 0; q < 8; ++q){
        int l = l0 + jb + q; int pos = rev ? (Ln-1-l) : l;
        uv[q] = bfr(src[(long)pos*Di + d]);
      }
      #pragma unroll
      for (int q = 0; q < 8; ++q){
        int j = jb + q;
        float xv = bias;
        #pragma unroll
        for (int r = 0; r < 6; ++r) xv += w[r]*sdt[j*6 + r];
        float dl, rr; sp_decay(xv, dl, rr);
        float du = dl * uv[q];
        float Bv[16];
        *(float4*)&Bv[0]  = *(const float4*)&sB[j*16];
        *(float4*)&Bv[4]  = *(const float4*)&sB[j*16+4];
        *(float4*)&Bv[8]  = *(const float4*)&sB[j*16+8];
        *(float4*)&Bv[12] = *(const float4*)&sB[j*16+12];
        float r2 = rr*rr, r3 = r2*rr, r4 = r2*r2, r8 = r4*r4, r12 = r8*r4;
        float S4[4] = {rr, r2, r3, r4};
        float B4[4] = {1.f, r4, r8, r12};
        #pragma unroll
        for (int n = 0; n < 16; ++n)
          h[n] = (B4[n>>2]*S4[n&3])*h[n] + du*Bv[n];
        S += dl;
      }
    }
  } else {
    for (int jb = 0; jb < CH; jb += 8){
      float uv[8];
      #pragma unroll
      for (int q = 0; q < 8; ++q){
        int l = l0 + jb + q; int pos = rev ? (Ln-1-l) : l;
        uv[q] = bfr(src[(long)pos*Di + d]);
      }
      #pragma unroll
      for (int q = 0; q < 8; ++q){
        int j = jb + q;
        float dl = bias;
        #pragma unroll
        for (int r = 0; r < 6; ++r) dl += w[r]*sdt[j*6 + r];
        dl = splus(dl);
        float du = dl * uv[q];
        float Bv[16];
        *(float4*)&Bv[0]  = *(const float4*)&sB[j*16];
        *(float4*)&Bv[4]  = *(const float4*)&sB[j*16+4];
        *(float4*)&Bv[8]  = *(const float4*)&sB[j*16+8];
        *(float4*)&Bv[12] = *(const float4*)&sB[j*16+12];
        #pragma unroll
        for (int n = 0; n < 16; ++n) h[n] = __expf(dl*a[n])*h[n] + du*Bv[n];
        S += dl;
      }
    }
  }
  long ci = (long)(b*Kn + k)*Gc + g;
  Sb[ci*Di + d] = S;
  float4* qp = (float4*)(Qb + ci*3072 + (long)d*16);
  qp[0] = make_float4(h[0], h[1], h[2], h[3]);
  qp[1] = make_float4(h[4], h[5], h[6], h[7]);
  qp[2] = make_float4(h[8], h[9], h[10], h[11]);
  qp[3] = make_float4(h[12], h[13], h[14], h[15]);
}
__global__ __launch_bounds__(192,3) void k_scan1_gen(const u16* xcLD, const u16* xcTLD, const u16* dtsg,
                                                     const u32* BCg, const void* Alog, const void* dtw,
                                                     const void* dtb, float* Sb, float* Qb,
                                                     const int* flag, const int* flag2){
  __shared__ float sdt[384];
  __shared__ float sB[1024];
  int f = *flag, f2 = *flag2;
  if (f && f2) return;                   // fast kernel handled it
  if (f) scan1_body<float>(xcLD, xcTLD, dtsg, BCg, (const float*)Alog, (const float*)dtw,
                           (const float*)dtb, Sb, Qb, sdt, sB, f2);
  else   scan1_body<bf16 >(xcLD, xcTLD, dtsg, BCg, (const bf16* )Alog, (const bf16* )dtw,
                           (const bf16* )dtb, Sb, Qb, sdt, sB, f2);
}

// ---------------------- cross-chunk fixup: Hin[g] = scan of (exp(a*S), Q) over g
template<typename T>
__device__ void fix_body(const float* Sb, const float* Qb, const T* Alog, float* Hin){
  int bk = blockIdx.x >> 2, qr = blockIdx.x & 3;
  int s0 = qr*768 + threadIdx.x;
  float aa[3], hh[3];
  #pragma unroll
  for (int q = 0; q < 3; ++q){
    int s = s0 + 256*q;
    aa[q] = -__expf(ldv(Alog, s));
    hh[q] = 0.f;
  }
  for (int g = 0; g < Gc; ++g){
    long ci = (long)bk*Gc + g;
    #pragma unroll
    for (int q = 0; q < 3; ++q){
      int s = s0 + 256*q;
      Hin[ci*3072 + s] = hh[q];
      hh[q] = __expf(aa[q]*Sb[ci*Di + (s >> 4)])*hh[q] + Qb[ci*3072 + s];
    }
  }
}
__global__ __launch_bounds__(256) void k_fix(const float* Sb, const float* Qb, const void* Alog,
                                             float* Hin, const int* flag){
  if (*flag) fix_body<float>(Sb, Qb, (const float*)Alog, Hin);
  else       fix_body<bf16 >(Sb, Qb, (const bf16* )Alog, Hin);
}

// ======================= SCAN PASS 2 =======================
__global__ __launch_bounds__(192,3) void k_scan2_fast(const u16* xcLD, const u16* xcTLD,
                                                      const u16* dtsg, const u32* BCg,
                                                      const void* dtw, const void* dtb,
                                                      const float* Hin, u16* ys,
                                                      const int* flag, const int* flag2){
  if (!(*flag && *flag2)) return;
  __shared__ float sdt[384];
  __shared__ float sB[1024];
  __shared__ float sC[1024];
  const float* dtwf = (const float*)dtw;
  const float* dtbf = (const float*)dtb;
  int tid = threadIdx.x, blk = blockIdx.x;
  int g = blk & (Gc-1); int k = (blk >> 6) & 3; int b = blk >> 8;
  bool rev = k >= 2, odd = k & 1;
  int d = tid;
  const u16* src = (odd ? xcTLD : xcLD) + (long)b*Ln*Di;
  const u16* dlg = dtsg + (long)(b*Kn + k)*Ln*6;
  const u32* bcg = BCg + (long)(b*Kn + k)*Ln*16;
  u16* yb = ys + (long)(b*Kn + k)*Ln*Di;
  float w[6], h[16];
  #pragma unroll
  for (int r = 0; r < 6; ++r) w[r] = dtwf[((long)k*Di + d)*6 + r];
  float bias = dtbf[k*Di + d];
  long ci = (long)(b*Kn + k)*Gc + g;
  {
    const float4* hp = (const float4*)(Hin + ci*3072 + (long)d*16);
    float4 h0 = hp[0], h1 = hp[1], h2 = hp[2], h3 = hp[3];
    h[0]=h0.x; h[1]=h0.y; h[2]=h0.z; h[3]=h0.w;
    h[4]=h1.x; h[5]=h1.y; h[6]=h1.z; h[7]=h1.w;
    h[8]=h2.x; h[9]=h2.y; h[10]=h2.z; h[11]=h2.w;
    h[12]=h3.x; h[13]=h3.y; h[14]=h3.z; h[15]=h3.w;
  }
  int l0 = g*CH;
  for (int i = tid; i < 48; i += 192){
    const u16* sp8 = dlg + (long)l0*6 + i*8;
    ushort4 v0 = *(const ushort4*)sp8;
    ushort4 v1 = *(const ushort4*)(sp8 + 4);
    float* dp = &sdt[i*8];
    dp[0]=bfr(v0.x); dp[1]=bfr(v0.y); dp[2]=bfr(v0.z); dp[3]=bfr(v0.w);
    dp[4]=bfr(v1.x); dp[5]=bfr(v1.y); dp[6]=bfr(v1.z); dp[7]=bfr(v1.w);
  }
  for (int i = tid; i < 256; i += 192){
    uint4 v = *(const uint4*)(bcg + (long)l0*16 + i*4);
    sB[i*4+0] = bfr((u16)(v.x & 0xffff)); sC[i*4+0] = bfr((u16)(v.x >> 16));
    sB[i*4+1] = bfr((u16)(v.y & 0xffff)); sC[i*4+1] = bfr((u16)(v.y >> 16));
    sB[i*4+2] = bfr((u16)(v.z & 0xffff)); sC[i*4+2] = bfr((u16)(v.z >> 16));
    sB[i*4+3] = bfr((u16)(v.w & 0xffff)); sC[i*4+3] = bfr((u16)(v.w >> 16));
  }
  __syncthreads();
  for (int jb = 0; jb < CH; jb += 16){
    float uv[16];
    #pragma unroll
    for (int q = 0; q < 16; ++q){
      int l = l0 + jb + q; int pos = rev ? (Ln-1-l) : l;
      uv[q] = bfr(src[(long)pos*Di + d]);
    }
    #pragma unroll
    for (int q = 0; q < 16; ++q){
      int j = jb + q;
      float xv = bias;
      #pragma unroll
      for (int r = 0; r < 6; ++r) xv += w[r]*sdt[j*6 + r];
      float dl, rr; sp_decay(xv, dl, rr);
      float du = dl * uv[q];
      float Bv[16], Cv[16];
      *(float4*)&Bv[0]  = *(const float4*)&sB[j*16];
      *(float4*)&Bv[4]  = *(const float4*)&sB[j*16+4];
      *(float4*)&Bv[8]  = *(const float4*)&sB[j*16+8];
      *(float4*)&Bv[12] = *(const float4*)&sB[j*16+12];
      *(float4*)&Cv[0]  = *(const float4*)&sC[j*16];
      *(float4*)&Cv[4]  = *(const float4*)&sC[j*16+4];
      *(float4*)&Cv[8]  = *(const float4*)&sC[j*16+8];
      *(float4*)&Cv[12] = *(const float4*)&sC[j*16+12];
      float r2 = rr*rr, r3 = r2*rr, r4 = r2*r2, r8 = r4*r4, r12 = r8*r4;
      float S4[4] = {rr, r2, r3, r4};
      float B4[4] = {1.f, r4, r8, r12};
      float y = 0.f;
      #pragma unroll
      for (int n = 0; n < 16; ++n){
        h[n] = (B4[n>>2]*S4[n&3])*h[n] + du*Bv[n];
        y += h[n]*Cv[n];
      }
      int l = l0 + j; int le = rev ? (Ln-1-l) : l;
      int sp = odd ? ((le & 63)*64 + (le >> 6)) : le;
      yb[(long)sp*Di + d] = fbr(y);
    }
  }
}

template<typename T>
__device__ void scan2_body(const u16* xcLD, const u16* xcTLD, const u16* dtsg, const u32* BCg,
                           const T* Alog, const T* dtw, const T* dtb, const float* Hin,
                           u16* ys, float* sdt, float* sB, float* sC, int fastA){
  int tid = threadIdx.x, blk = blockIdx.x;
  int g = blk & (Gc-1); int k = (blk >> 6) & 3; int b = blk >> 8;
  bool rev = k >= 2, odd = k & 1;
  int d = tid;
  const u16* src = (odd ? xcTLD : xcLD) + (long)b*Ln*Di;
  const u16* dlg = dtsg + (long)(b*Kn + k)*Ln*6;
  const u32* bcg = BCg + (long)(b*Kn + k)*Ln*16;
  u16* yb = ys + (long)(b*Kn + k)*Ln*Di;
  float w[6], h[16], a[16];
  #pragma unroll
  for (int r = 0; r < 6; ++r) w[r] = ldv(dtw, ((long)k*Di + d)*6 + r);
  float bias = ldv(dtb, k*Di + d);
  long ci = (long)(b*Kn + k)*Gc + g;
  {
    const float4* hp = (const float4*)(Hin + ci*3072 + (long)d*16);
    float4 h0 = hp[0], h1 = hp[1], h2 = hp[2], h3 = hp[3];
    h[0]=h0.x; h[1]=h0.y; h[2]=h0.z; h[3]=h0.w;
    h[4]=h1.x; h[5]=h1.y; h[6]=h1.z; h[7]=h1.w;
    h[8]=h2.x; h[9]=h2.y; h[10]=h2.z; h[11]=h2.w;
    h[12]=h3.x; h[13]=h3.y; h[14]=h3.z; h[15]=h3.w;
  }
  if (!fastA){
    #pragma unroll
    for (int n = 0; n < 16; ++n) a[n] = -__expf(ldv(Alog, (long)d*16 + n));
  }
  int l0 = g*CH;
  for (int i = tid; i < 48; i += 192){
    const u16* sp8 = dlg + (long)l0*6 + i*8;
    ushort4 v0 = *(const ushort4*)sp8;
    ushort4 v1 = *(const ushort4*)(sp8 + 4);
    float* dp = &sdt[i*8];
    dp[0]=bfr(v0.x); dp[1]=bfr(v0.y); dp[2]=bfr(v0.z); dp[3]=bfr(v0.w);
    dp[4]=bfr(v1.x); dp[5]=bfr(v1.y); dp[6]=bfr(v1.z); dp[7]=bfr(v1.w);
  }
  for (int i = tid; i < 256; i += 192){
    uint4 v = *(const uint4*)(bcg + (long)l0*16 + i*4);
    sB[i*4+0] = bfr((u16)(v.x & 0xffff)); sC[i*4+0] = bfr((u16)(v.x >> 16));
    sB[i*4+1] = bfr((u16)(v.y & 0xffff)); sC[i*4+1] = bfr((u16)(v.y >> 16));
    sB[i*4+2] = bfr((u16)(v.z & 0xffff)); sC[i*4+2] = bfr((u16)(v.z >> 16));
    sB[i*4+3] = bfr((u16)(v.w & 0xffff)); sC[i*4+3] = bfr((u16)(v.w >> 16));
  }
  __syncthreads();
  if (fastA){
    for (int jb = 0; jb < CH; jb += 8){
      float uv[8];
      #pragma unroll
      for (int q = 0; q < 8; ++q){
        int l = l0 + jb + q; int pos = rev ? (Ln-1-l) : l;
        uv[q] = bfr(src[(long)pos*Di + d]);
      }
      #pragma unroll
      for (int q = 0; q < 8; ++q){
        int j = jb + q;
        float xv = bias;
        #pragma unroll
        for (int r = 0; r < 6; ++r) xv += w[r]*sdt[j*6 + r];
        float dl, rr; sp_decay(xv, dl, rr);
        float du = dl * uv[q];
        float Bv[16], Cv[16];
        *(float4*)&Bv[0]  = *(const float4*)&sB[j*16];
        *(float4*)&Bv[4]  = *(const float4*)&sB[j*16+4];
        *(float4*)&Bv[8]  = *(const float4*)&sB[j*16+8];
        *(float4*)&Bv[12] = *(const float4*)&sB[j*16+12];
        *(float4*)&Cv[0]  = *(const float4*)&sC[j*16];
        *(float4*)&Cv[4]  = *(const float4*)&sC[j*16+4];
        *(float4*)&Cv[8]  = *(const float4*)&sC[j*16+8];
        *(float4*)&Cv[12] = *(const float4*)&sC[j*16+12];
        float r2 = rr*rr, r3 = r2*rr, r4 = r2*r2, r8 = r4*r4, r12 = r8*r4;
        float S4[4] = {rr, r2, r3, r4};
        float B4[4] = {1.f, r4, r8, r12};
        float y = 0.f;
        #pragma unroll
        for (int n = 0; n < 16; ++n){
          h[n] = (B4[n>>2]*S4[n&3])*h[n] + du*Bv[n];
          y += h[n]*Cv[n];
        }
        int l = l0 + j; int le = rev ? (Ln-1-l) : l;
        int sp = odd ? ((le & 63)*64 + (le >> 6)) : le;
        yb[(long)sp*Di + d] = fbr(y);
      }
    }
  } else {
    for (int jb = 0; jb < CH; jb += 8){
      float uv[8];
      #pragma unroll
      for (int q = 0; q < 8; ++q){
        int l = l0 + jb + q; int pos = rev ? (Ln-1-l) : l;
        uv[q] = bfr(src[(long)pos*Di + d]);
      }
      #pragma unroll
      for (int q = 0; q < 8; ++q){
        int j = jb + q;
        float dl = bias;
        #pragma unroll
        for (int r = 0; r < 6; ++r) dl += w[r]*sdt[j*6 + r];
        dl = splus(dl);
        float du = dl * uv[q];
        float Bv[16], Cv[16];
        *(float4*)&Bv[0]  = *(const float4*)&sB[j*16];
        *(float4*)&Bv[4]  = *(const float4*)&sB[j*16+4];
        *(float4*)&Bv[8]  = *(const float4*)&sB[j*16+8];
        *(float4*)&Bv[12] = *(const float4*)&sB[j*16+12];
        *(float4*)&Cv[0]  = *(const float4*)&sC[j*16];
        *(float4*)&Cv[4]  = *(const float4*)&sC[j*16+4];
        *(float4*)&Cv[8]  = *(const float4*)&sC[j*16+8];
        *(float4*)&Cv[12] = *(const float4*)&sC[j*16+12];
        float y = 0.f;
        #pragma unroll
        for (int n = 0; n < 16; ++n){
          h[n] = __expf(dl*a[n])*h[n] + du*Bv[n];
          y += h[n]*Cv[n];
        }
        int l = l0 + j; int le = rev ? (Ln-1-l) : l;
        int sp = odd ? ((le & 63)*64 + (le >> 6)) : le;
        yb[(long)sp*Di + d] = fbr(y);
      }
    }
  }
}
__global__ __launch_bounds__(192,3) void k_scan2_gen(const u16* xcLD, const u16* xcTLD, const u16* dtsg,
                                                     const u32* BCg, const void* Alog, const void* dtw,
                                                     const void* dtb, const float* Hin, u16* ys,
                                                     const int* flag, const int* flag2){
  __shared__ float sdt[384];
  __shared__ float sB[1024];
  __shared__ float sC[1024];
  int f = *flag, f2 = *flag2;
  if (f && f2) return;                   // fast kernel handled it
  if (f) scan2_body<float>(xcLD, xcTLD, dtsg, BCg, (const float*)Alog, (const float*)dtw,
                           (const float*)dtb, Hin, ys, sdt, sB, sC, f2);
  else   scan2_body<bf16 >(xcLD, xcTLD, dtsg, BCg, (const bf16* )Alog, (const bf16* )dtw,
                           (const bf16* )dtb, Hin, ys, sdt, sB, sC, f2);
}

// ------- merge + skip + LayerNorm + gate + out_proj (MFMA, 32 positions/block)
template<typename T>
__device__ void out_body(const u16* ys, const u16* xcLD, const u16* Z, const T* Dsv,
                         const T* lnw, const T* lnb, const T* wo, T* out, long obase,
                         u16* ty, float* sDs){
  int blk = blockIdx.x;
  int b = blk >> 7; int rem = blk & 127; int h = rem >> 1; int half = rem & 1;
  int tid = threadIdx.x;
  int p0 = h*64 + half*32;
  const u16* xcb = xcLD + (long)b*Ln*Di;
  const u16* Zb  = Z + (long)b*Ln*Di;
  const u16* pl0 = ys + (long)(b*Kn + 0)*Ln*Di;
  const u16* pl1 = ys + (long)(b*Kn + 1)*Ln*Di;
  const u16* pl2 = ys + (long)(b*Kn + 2)*Ln*Di;
  const u16* pl3 = ys + (long)(b*Kn + 3)*Ln*Di;
  if (tid < Di)
    sDs[tid] = ldv(Dsv, tid) + ldv(Dsv, Di+tid) + ldv(Dsv, 2*Di+tid) + ldv(Dsv, 3*Di+tid);
  __syncthreads();
  for (int i = tid; i < 768; i += 256){
    int j = i / 24, c8 = (i % 24) * 8;
    int wc = half*32 + j;
    long ls = (long)(p0 + j)*Di + c8;
    long lt = (long)(wc*64 + h)*Di + c8;
    ushort4 a0 = *(const ushort4*)(pl0 + ls); ushort4 a1 = *(const ushort4*)(pl0 + ls + 4);
    ushort4 b0 = *(const ushort4*)(pl2 + ls); ushort4 b1 = *(const ushort4*)(pl2 + ls + 4);
    ushort4 c0 = *(const ushort4*)(pl1 + lt); ushort4 c1 = *(const ushort4*)(pl1 + lt + 4);
    ushort4 d0 = *(const ushort4*)(pl3 + lt); ushort4 d1 = *(const ushort4*)(pl3 + lt + 4);
    ushort4 x0 = *(const ushort4*)(xcb + ls); ushort4 x1 = *(const ushort4*)(xcb + ls + 4);
    u16* tp = &ty[j*200 + c8];
    tp[0] = fbr(bfr(a0.x)+bfr(b0.x)+bfr(c0.x)+bfr(d0.x) + sDs[c8+0]*bfr(x0.x));
    tp[1] = fbr(bfr(a0.y)+bfr(b0.y)+bfr(c0.y)+bfr(d0.y) + sDs[c8+1]*bfr(x0.y));
    tp[2] = fbr(bfr(a0.z)+bfr(b0.z)+bfr(c0.z)+bfr(d0.z) + sDs[c8+2]*bfr(x0.z));
    tp[3] = fbr(bfr(a0.w)+bfr(b0.w)+bfr(c0.w)+bfr(d0.w) + sDs[c8+3]*bfr(x0.w));
    tp[4] = fbr(bfr(a1.x)+bfr(b1.x)+bfr(c1.x)+bfr(d1.x) + sDs[c8+4]*bfr(x1.x));
    tp[5] = fbr(bfr(a1.y)+bfr(b1.y)+bfr(c1.y)+bfr(d1.y) + sDs[c8+5]*bfr(x1.y));
    tp[6] = fbr(bfr(a1.z)+bfr(b1.z)+bfr(c1.z)+bfr(d1.z) + sDs[c8+6]*bfr(x1.z));
    tp[7] = fbr(bfr(a1.w)+bfr(b1.w)+bfr(c1.w)+bfr(d1.w) + sDs[c8+7]*bfr(x1.w));
  }
  __syncthreads();
  int jj = tid >> 3, part = tid & 7;
  float s = 0.f, s2 = 0.f;
  for (int cix = part*24; cix < part*24 + 24; ++cix){
    float v = bfr(ty[jj*200 + cix]); s += v; s2 += v*v;
  }
  s += __shfl_xor(s, 1); s2 += __shfl_xor(s2, 1);
  s += __shfl_xor(s, 2); s2 += __shfl_xor(s2, 2);
  s += __shfl_xor(s, 4); s2 += __shfl_xor(s2, 4);
  float mu = s * (1.f/192.f);
  float var = s2 * (1.f/192.f) - mu*mu;
  float rstd = rsqrtf(fmaxf(var, 0.f) + 1e-5f);
  long zbase = (long)(p0 + jj)*Di;
  for (int cix = part*24; cix < part*24 + 24; ++cix){
    float zv = bfr(Zb[zbase + cix]);
    float gt = zv / (1.f + __expf(-zv));
    float yn = (bfr(ty[jj*200 + cix]) - mu) * rstd * ldv(lnw, cix) + ldv(lnb, cix);
    ty[jj*200 + cix] = fbr(yn * gt);
  }
  __syncthreads();
  int wid = tid >> 6, lane = tid & 63;
  int wm = wid & 1, wn = wid >> 1;
  int lr = lane & 15, lh = lane >> 4;
  f32x4 acc[3] = {};
  #pragma unroll
  for (int ks = 0; ks < 6; ++ks){
    int k0 = ks*32 + lh*8;
    bf16x8 av = *(const bf16x8*)&ty[(wm*16 + lr)*200 + k0];
    #pragma unroll
    for (int n = 0; n < 3; ++n){
      bf16x8 b8 = ldb8(wo + (long)(wn*48 + n*16 + lr)*192 + k0);
      acc[n] = __builtin_amdgcn_mfma_f32_16x16x32_bf16(av, b8, acc[n], 0, 0, 0);
    }
  }
  #pragma unroll
  for (int n = 0; n < 3; ++n){
    int col = wn*48 + n*16 + lr;
    #pragma unroll
    for (int r = 0; r < 4; ++r){
      long row = (long)b*Ln + p0 + wm*16 + lh*4 + r;
      stv(out, obase + row*Cm + col, acc[n][r]);
    }
  }
}
__global__ __launch_bounds__(256) void k_out(const u16* ys, const u16* xcLD, const u16* Z,
                                             const void* Dsv, const void* lnw, const void* lnb,
                                             const void* wo, void* out, long obase, const int* flag){
  __shared__ u16 ty[32*200];
  __shared__ float sDs[Di];
  if (*flag) out_body<float>(ys, xcLD, Z, (const float*)Dsv, (const float*)lnw, (const float*)lnb,
                             (const float*)wo, (float*)out, obase, ty, sDs);
  else       out_body<bf16 >(ys, xcLD, Z, (const bf16* )Dsv, (const bf16* )lnw, (const bf16* )lnb,
                             (const bf16* )wo, (bf16* )out, obase, ty, sDs);
}

extern "C" void kernel_launch(void* const* d_in, const int* in_sizes, int n_in,
                              void* d_out, int out_size, void* d_ws, size_t ws_size,
                              hipStream_t stream){
  const void* x    = d_in[0];
  const void* ipw  = d_in[1];
  const void* cw   = d_in[2];
  const void* cb   = d_in[3];
  const void* xpw  = d_in[4];
  const void* dtw  = d_in[5];
  const void* dtb  = d_in[6];
  const void* Alog = d_in[7];
  const void* Dsv  = d_in[8];
  const void* lnw  = d_in[9];
  const void* lnb  = d_in[10];
  const void* wo   = d_in[11];

  const size_t PLANE = (size_t)Ln*Di*2;
  const size_t YSB   = (size_t)Kn*Ln*Di*2;
  const size_t SBB   = (size_t)Kn*Gc*Di*4;
  const size_t QBB   = (size_t)Kn*Gc*Di*Ns*4;
  const size_t HIB   = QBB;
  const size_t perB  = 4*PLANE + YSB + SBB + QBB + HIB;
  int Bc = 1;
  for (int c : {8, 4, 2, 1}) if (256 + (size_t)c*perB <= ws_size){ Bc = c; break; }
  int nch = 8 / Bc;

  char* base = (char*)d_ws;
  int*  flag  = (int*)base;
  int*  flag2 = (int*)(base + 8);
  u16* Z     = (u16*)(base + 256);
  u16* xcLD  = Z     + (size_t)Bc*Ln*Di;
  u16* xcTLD = xcLD  + (size_t)Bc*Ln*Di;
  u16* Xb    = xcTLD + (size_t)Bc*Ln*Di;
  u16* ys    = Xb    + (size_t)Bc*Ln*Di;
  float* Sb  = (float*)(ys + (size_t)Bc*Kn*Ln*Di);
  float* Qb  = Sb + (size_t)Bc*Kn*Gc*Di;
  float* Hin = Qb + (size_t)Bc*Kn*Gc*Di*Ns;
  u16* dts   = Xb;
  u32* BC    = (u32*)(dts + (size_t)Bc*Kn*Ln*6);

  k_detect<<<1, 256, 0, stream>>>((const u16*)x, Alog, flag, flag2);

  for (int ch = 0; ch < nch; ++ch){
    long xoff = (long)ch*Bc*Ln*Cm;
    k_inproj <<<Bc*Ln/64,     256, 0, stream>>>(x, xoff, ipw, Xb, Z, flag);
    k_conv   <<<Bc*Hn*3,      256, 0, stream>>>(Xb, cw, cb, xcLD, xcTLD, flag);
    k_proj   <<<Bc*(Ln/64)*2, 256, 0, stream>>>(xcLD, xcTLD, xpw, dts, BC, flag);
    k_scan1_fast<<<Bc*Kn*Gc,  192, 0, stream>>>(xcLD, xcTLD, dts, BC, dtw, dtb, Sb, Qb, flag, flag2);
    k_scan1_gen <<<Bc*Kn*Gc,  192, 0, stream>>>(xcLD, xcTLD, dts, BC, Alog, dtw, dtb, Sb, Qb, flag, flag2);
    k_fix    <<<Bc*Kn*4,      256, 0, stream>>>(Sb, Qb, Alog, Hin, flag);
    k_scan2_fast<<<Bc*Kn*Gc,  192, 0, stream>>>(xcLD, xcTLD, dts, BC, dtw, dtb, Hin, ys, flag, flag2);
    k_scan2_gen <<<Bc*Kn*Gc,  192, 0, stream>>>(xcLD, xcTLD, dts, BC, Alog, dtw, dtb, Hin, ys, flag, flag2);
    k_out    <<<Bc*Hn*2,      256, 0, stream>>>(ys, xcLD, Z, Dsv, lnw, lnb, wo, d_out, xoff, flag);
  }
}

// Round 12
// 352.210 us; speedup vs baseline: 1.9051x; 1.9051x over previous
//
#include <hip/hip_runtime.h>
#include <hip/hip_bf16.h>

typedef __hip_bfloat16 bf16;
typedef unsigned short u16;
typedef unsigned int   u32;

constexpr int Hn=64, Wn=64, Cm=96, Ln=4096, Di=192, Kn=4, Ns=16, Rr=6;
constexpr int Gc=64, CH=64;   // 64 chunks of 64 positions

typedef __attribute__((ext_vector_type(8))) short bf16x8;
typedef __attribute__((ext_vector_type(4))) float f32x4;

static __device__ __forceinline__ float ldv(const float* p, long i){ return p[i]; }
static __device__ __forceinline__ float ldv(const bf16*  p, long i){ return __bfloat162float(p[i]); }
static __device__ __forceinline__ void  stv(float* p, long i, float v){ p[i] = v; }
static __device__ __forceinline__ void  stv(bf16*  p, long i, float v){ p[i] = __float2bfloat16(v); }
static __device__ __forceinline__ float bfr(u16 u){ return __uint_as_float((u32)u << 16); }
static __device__ __forceinline__ u16   fbr(float f){ bf16 h = __float2bfloat16(f); return *(u16*)&h; }
static __device__ __forceinline__ float4 ldv4(const float* p, long i){ return *(const float4*)(p + i); }
static __device__ __forceinline__ float4 ldv4(const bf16* p, long i){
  ushort4 u = *(const ushort4*)(p + i);
  return make_float4(bfr(u.x), bfr(u.y), bfr(u.z), bfr(u.w));
}
static __device__ __forceinline__ float splus(float x){ return (x > 15.f) ? x : log1pf(__expf(x)); }

// load 8 contiguous elems as a bf16 MFMA fragment (convert if f32)
static __device__ __forceinline__ bf16x8 ldb8(const float* p){
  float4 a = *(const float4*)p;
  float4 b = *(const float4*)(p + 4);
  bf16x8 r;
  r[0]=(short)fbr(a.x); r[1]=(short)fbr(a.y); r[2]=(short)fbr(a.z); r[3]=(short)fbr(a.w);
  r[4]=(short)fbr(b.x); r[5]=(short)fbr(b.y); r[6]=(short)fbr(b.z); r[7]=(short)fbr(b.w);
  return r;
}
static __device__ __forceinline__ bf16x8 ldb8(const bf16* p){
  return *(const bf16x8*)p;
}
// store 8 elems into LDS as bf16 (convert if f32)
static __device__ __forceinline__ void st8(u16* dst, const float* src){
  float4 a = *(const float4*)src;
  float4 b = *(const float4*)(src + 4);
  dst[0]=fbr(a.x); dst[1]=fbr(a.y); dst[2]=fbr(a.z); dst[3]=fbr(a.w);
  dst[4]=fbr(b.x); dst[5]=fbr(b.y); dst[6]=fbr(b.z); dst[7]=fbr(b.w);
}
static __device__ __forceinline__ void st8(u16* dst, const bf16* src){
  *(ushort4*)dst       = *(const ushort4*)src;
  *(ushort4*)(dst + 4) = *(const ushort4*)(src + 4);
}

// ---------------- dtype detector (f32 vs bf16) + Alog structure detector
__global__ void k_detect(const u16* x, const void* Alog, int* flag, int* flag2){
  __shared__ int cnt, cnt2;
  if (threadIdx.x == 0){ cnt = 0; cnt2 = 0; }
  __syncthreads();
  int local = 0;
  for (int i = threadIdx.x; i < 8192; i += 256){
    int e = (x[i] >> 7) & 0xFF;
    if (e != 0 && (e < 90 || e > 164)) local++;
  }
  atomicAdd(&cnt, local);
  __syncthreads();
  int f = (cnt > 400) ? 1 : 0;          // 1 => float32 inputs
  int bad = 0;
  for (int i = threadIdx.x; i < Di*Ns; i += 256){
    float v = f ? ((const float*)Alog)[i] : bfr(((const u16*)Alog)[i]);
    float ex = __logf((float)((i & 15) + 1));
    if (fabsf(v - ex) > 1e-5f) bad++;
  }
  atomicAdd(&cnt2, bad);
  __syncthreads();
  if (threadIdx.x == 0){ *flag = f; *flag2 = (cnt2 == 0) ? 1 : 0; }
}

// ---------------------------------------------------------------- in_proj GEMM (MFMA)
template<typename T>
__device__ void inproj_body(const T* x, const T* w, u16* Xb, u16* Z, u16* sA, u16* sC){
  int tid = threadIdx.x;
  long p0 = (long)blockIdx.x * 64;
  for (int i = tid; i < 768; i += 256){
    int r = i / 12, c = (i % 12) * 8;
    st8(&sA[r*104 + c], x + p0*96 + (long)r*96 + c);
  }
  __syncthreads();
  int wid = tid >> 6, lane = tid & 63;
  int lr = lane & 15, lh = lane >> 4;
  int colbase = wid * 96;
  f32x4 acc[4][6] = {};
  #pragma unroll
  for (int ks = 0; ks < 3; ++ks){
    int k0 = ks*32 + lh*8;
    bf16x8 af[4];
    #pragma unroll
    for (int m = 0; m < 4; ++m)
      af[m] = *(const bf16x8*)&sA[(m*16 + lr)*104 + k0];
    #pragma unroll
    for (int n = 0; n < 6; ++n){
      bf16x8 b8 = ldb8(w + (long)(colbase + n*16 + lr)*96 + k0);
      #pragma unroll
      for (int m = 0; m < 4; ++m)
        acc[m][n] = __builtin_amdgcn_mfma_f32_16x16x32_bf16(af[m], b8, acc[m][n], 0, 0, 0);
    }
  }
  #pragma unroll
  for (int n = 0; n < 6; ++n){
    int gc = colbase + n*16 + lr;
    #pragma unroll
    for (int m = 0; m < 4; ++m){
      #pragma unroll
      for (int r = 0; r < 4; ++r)
        sC[(m*16 + lh*4 + r)*392 + gc] = fbr(acc[m][n][r]);
    }
  }
  __syncthreads();
  for (int i = tid; i < 3072; i += 256){
    int r = i / 48, c = (i % 48) * 8;
    ushort4 v0 = *(const ushort4*)&sC[r*392 + c];
    ushort4 v1 = *(const ushort4*)&sC[r*392 + c + 4];
    u16* dst = (c < 192) ? (Xb + (p0 + r)*192 + c) : (Z + (p0 + r)*192 + (c - 192));
    *(ushort4*)dst       = v0;
    *(ushort4*)(dst + 4) = v1;
  }
}
__global__ __launch_bounds__(256) void k_inproj(const void* x, long xoff, const void* w,
                                                u16* Xb, u16* Z, const int* flag){
  __shared__ u16 sA[64*104];
  __shared__ u16 sC[64*392];
  if (*flag) inproj_body<float>((const float*)x + xoff, (const float*)w, Xb, Z, sA, sC);
  else       inproj_body<bf16 >((const bf16* )x + xoff, (const bf16* )w, Xb, Z, sA, sC);
}

// ------------------- depthwise conv3x3 + SiLU -> xcLD (L,D) and xcTLD (Lt,D)
template<typename T>
__device__ void conv_body(const u16* Xb, const T* cw, const T* cb,
                          u16* xcLD, u16* xcTLD, float* wv, float* bv){
  int blk = blockIdx.x;
  int dq = blk % 3; int hb = blk / 3; int h = hb & 63; int b = hb >> 6;
  int tid = threadIdx.x;
  int d0 = dq*64;
  for (int i = tid; i < 576; i += 256){
    int c = i & 63, t = i >> 6;
    wv[t*64 + c] = ldv(cw, (long)(d0 + c)*9 + t);
  }
  if (tid < 64) bv[tid] = ldv(cb, d0 + tid);
  __syncthreads();
  const u16* Xbb = Xb + (long)b*Ln*Di;
  u16* xa = xcLD  + (long)b*Ln*Di;
  u16* xb = xcTLD + (long)b*Ln*Di;
  int c8l = (tid & 7)*8;
  int d = d0 + c8l;
  float4 wf[9][2];
  #pragma unroll
  for (int t = 0; t < 9; ++t){
    wf[t][0] = *(const float4*)&wv[t*64 + c8l];
    wf[t][1] = *(const float4*)&wv[t*64 + c8l + 4];
  }
  float bss[8];
  #pragma unroll
  for (int q = 0; q < 8; ++q) bss[q] = bv[c8l + q];
  #pragma unroll
  for (int half = 0; half < 2; ++half){
    int w = (tid >> 3) + half*32;
    float acc[8];
    #pragma unroll
    for (int q = 0; q < 8; ++q) acc[q] = bss[q];
    #pragma unroll
    for (int dh = -1; dh <= 1; ++dh){
      int hh = h + dh;
      if ((unsigned)hh > 63u) continue;
      #pragma unroll
      for (int dw = -1; dw <= 1; ++dw){
        int ww = w + dw;
        if ((unsigned)ww > 63u) continue;
        int t = (dh+1)*3 + (dw+1);
        const u16* p = Xbb + (long)(hh*64 + ww)*Di + d;
        ushort4 v0 = *(const ushort4*)p;
        ushort4 v1 = *(const ushort4*)(p + 4);
        acc[0] += wf[t][0].x * bfr(v0.x);
        acc[1] += wf[t][0].y * bfr(v0.y);
        acc[2] += wf[t][0].z * bfr(v0.z);
        acc[3] += wf[t][0].w * bfr(v0.w);
        acc[4] += wf[t][1].x * bfr(v1.x);
        acc[5] += wf[t][1].y * bfr(v1.y);
        acc[6] += wf[t][1].z * bfr(v1.z);
        acc[7] += wf[t][1].w * bfr(v1.w);
      }
    }
    u16 o[8];
    #pragma unroll
    for (int q = 0; q < 8; ++q){
      float e = __expf(-acc[q]);
      float sv = acc[q] * __builtin_amdgcn_rcpf(1.f + e);
      o[q] = fbr(sv);
    }
    ushort4 s0; s0.x=o[0]; s0.y=o[1]; s0.z=o[2]; s0.w=o[3];
    ushort4 s1; s1.x=o[4]; s1.y=o[5]; s1.z=o[6]; s1.w=o[7];
    u16* pa = xa + (long)(h*64 + w)*Di + d;
    u16* pb = xb + (long)(w*64 + h)*Di + d;
    *(ushort4*)pa = s0; *(ushort4*)(pa + 4) = s1;
    *(ushort4*)pb = s0; *(ushort4*)(pb + 4) = s1;
  }
}
__global__ __launch_bounds__(256,4) void k_conv(const u16* Xb, const void* cw, const void* cb,
                                                u16* xcLD, u16* xcTLD, const int* flag){
  __shared__ float wv[576];
  __shared__ float bv[64];
  if (*flag) conv_body<float>(Xb, (const float*)cw, (const float*)cb, xcLD, xcTLD, wv, bv);
  else       conv_body<bf16 >(Xb, (const bf16* )cw, (const bf16* )cb, xcLD, xcTLD, wv, bv);
}

// --------------------------------------------- x_proj (MFMA): dts + packed B/C, scan order
template<typename T>
__device__ void proj_body(const u16* xcLD, const u16* xcTLD, const T* xpw,
                          u16* dtsg, u32* BCg, u16* sA){
  int tid = threadIdx.x;
  int s = blockIdx.x & 1;
  long q0 = (long)(blockIdx.x >> 1) * 64;
  const u16* src = (s ? xcTLD : xcLD) + q0*192;
  for (int i = tid; i < 1536; i += 256){
    int r = i / 24, c = (i % 24) * 8;
    const u16* sp = src + (long)r*192 + c;
    *(ushort4*)&sA[r*200 + c]     = *(const ushort4*)sp;
    *(ushort4*)&sA[r*200 + c + 4] = *(const ushort4*)(sp + 4);
  }
  __syncthreads();
  int wid = tid >> 6, lane = tid & 63;
  int lr = lane & 15, lh = lane >> 4;
  f32x4 acc[5] = {};
  #pragma unroll
  for (int ks = 0; ks < 6; ++ks){
    int k0 = ks*32 + lh*8;
    bf16x8 a = *(const bf16x8*)&sA[(wid*16 + lr)*200 + k0];
    #pragma unroll
    for (int f = 0; f < 5; ++f){
      int c = f*16 + lr;
      int cw;
      if (c < 38)      cw = s*38 + c;
      else if (c < 76) cw = (s+2)*38 + (c - 38);
      else             cw = 0;
      bf16x8 b8 = ldb8(xpw + (long)cw*192 + k0);
      acc[f] = __builtin_amdgcn_mfma_f32_16x16x32_bf16(a, b8, acc[f], 0, 0, 0);
    }
  }
  int row_l = wid*16 + lh*4;
  #pragma unroll
  for (int f = 0; f < 5; ++f){
    int c = f*16 + lr;
    if (c >= 76) continue;
    int k = (c < 38) ? s : s + 2;
    int t = (c < 38) ? c : c - 38;
    if (t >= 22) continue;
    #pragma unroll
    for (int r = 0; r < 4; ++r){
      long q = q0 + row_l + r;
      int b  = (int)(q >> 12);
      int ql = (int)(q & 4095);
      int l  = (k >= 2) ? (4095 - ql) : ql;
      long base = ((long)(b*4 + k))*4096 + l;
      if (t < 6){
        dtsg[base*6 + t] = fbr(acc[f][r]);
      } else {
        int n = t - 6;
        u32 v = (u32)fbr(acc[f][r]) | ((u32)fbr(acc[f+1][r]) << 16);
        BCg[base*16 + n] = v;
      }
    }
  }
}
__global__ __launch_bounds__(256) void k_proj(const u16* xcLD, const u16* xcTLD, const void* xpw,
                                              u16* dtsg, u32* BCg, const int* flag){
  __shared__ u16 sA[64*200];
  if (*flag) proj_body<float>(xcLD, xcTLD, (const float*)xpw, dtsg, BCg, sA);
  else       proj_body<bf16 >(xcLD, xcTLD, (const bf16* )xpw, dtsg, BCg, sA);
}

// softplus + decay pair: dl = softplus(xv), rr = exp(-dl) (reuses exp(xv))
static __device__ __forceinline__ void sp_decay(float xv, float& dl, float& rr){
  if (xv > 15.f){ dl = xv; rr = __expf(-xv); }
  else {
    float o = 1.f + __expf(xv);
    dl = __logf(o);
    rr = __builtin_amdgcn_rcpf(o);
  }
}

// ======================= SCAN PASS 1 =======================
// MEASURED-BEST (352us total, reproduced twice). FINAL ledger of failed
// restructures — this form is the local optimum, DO NOT touch:
//   (192,5) occupancy bound      -> spill, +290us (r2)
//   2-thread-per-d split         -> +55% VALU, +45us (r4)
//   u-prefetch double-buffer     -> carry spill, +70us (r6)
//   dl-aux via HBM (CH=128)      -> +200MB traffic, +44us (r9)
//   u-batch 16 (unrolled body)   -> 1GB spill, +320us (r11)
// Batch-8 is the register-liveness knee. Recompute beats memoization.
__global__ __launch_bounds__(192,3) void k_scan1_fast(const u16* xcLD, const u16* xcTLD,
                                                      const u16* dtsg, const u32* BCg,
                                                      const void* dtw, const void* dtb,
                                                      float* Sb, float* Qb,
                                                      const int* flag, const int* flag2){
  if (!(*flag && *flag2)) return;
  __shared__ float sdt[384];
  __shared__ float sB[1024];
  const float* dtwf = (const float*)dtw;
  const float* dtbf = (const float*)dtb;
  int tid = threadIdx.x, blk = blockIdx.x;
  int g = blk & (Gc-1); int k = (blk >> 6) & 3; int b = blk >> 8;
  bool rev = k >= 2, odd = k & 1;
  int d = tid;
  const u16* src = (odd ? xcTLD : xcLD) + (long)b*Ln*Di;
  const u16* dlg = dtsg + (long)(b*Kn + k)*Ln*6;
  const u32* bcg = BCg + (long)(b*Kn + k)*Ln*16;
  float w[6], h[16];
  #pragma unroll
  for (int r = 0; r < 6; ++r) w[r] = dtwf[((long)k*Di + d)*6 + r];
  float bias = dtbf[k*Di + d];
  #pragma unroll
  for (int n = 0; n < 16; ++n) h[n] = 0.f;
  float S = 0.f;
  int l0 = g*CH;
  for (int i = tid; i < 48; i += 192){
    const u16* sp8 = dlg + (long)l0*6 + i*8;
    ushort4 v0 = *(const ushort4*)sp8;
    ushort4 v1 = *(const ushort4*)(sp8 + 4);
    float* dp = &sdt[i*8];
    dp[0]=bfr(v0.x); dp[1]=bfr(v0.y); dp[2]=bfr(v0.z); dp[3]=bfr(v0.w);
    dp[4]=bfr(v1.x); dp[5]=bfr(v1.y); dp[6]=bfr(v1.z); dp[7]=bfr(v1.w);
  }
  for (int i = tid; i < 256; i += 192){
    uint4 v = *(const uint4*)(bcg + (long)l0*16 + i*4);
    sB[i*4+0] = bfr((u16)(v.x & 0xffff));
    sB[i*4+1] = bfr((u16)(v.y & 0xffff));
    sB[i*4+2] = bfr((u16)(v.z & 0xffff));
    sB[i*4+3] = bfr((u16)(v.w & 0xffff));
  }
  __syncthreads();
  for (int jb = 0; jb < CH; jb += 8){
    float uv[8];
    #pragma unroll
    for (int q = 0; q < 8; ++q){
      int l = l0 + jb + q; int pos = rev ? (Ln-1-l) : l;
      uv[q] = bfr(src[(long)pos*Di + d]);
    }
    #pragma unroll
    for (int q = 0; q < 8; ++q){
      int j = jb + q;
      float xv = bias;
      #pragma unroll
      for (int r = 0; r < 6; ++r) xv += w[r]*sdt[j*6 + r];
      float dl, rr; sp_decay(xv, dl, rr);
      float du = dl * uv[q];
      float Bv[16];
      *(float4*)&Bv[0]  = *(const float4*)&sB[j*16];
      *(float4*)&Bv[4]  = *(const float4*)&sB[j*16+4];
      *(float4*)&Bv[8]  = *(const float4*)&sB[j*16+8];
      *(float4*)&Bv[12] = *(const float4*)&sB[j*16+12];
      float r2 = rr*rr, r3 = r2*rr, r4 = r2*r2, r8 = r4*r4, r12 = r8*r4;
      float S4[4] = {rr, r2, r3, r4};
      float B4[4] = {1.f, r4, r8, r12};
      #pragma unroll
      for (int n = 0; n < 16; ++n)
        h[n] = (B4[n>>2]*S4[n&3])*h[n] + du*Bv[n];
      S += dl;
    }
  }
  long ci = (long)(b*Kn + k)*Gc + g;
  Sb[ci*Di + d] = S;
  float4* qp = (float4*)(Qb + ci*3072 + (long)d*16);
  qp[0] = make_float4(h[0], h[1], h[2], h[3]);
  qp[1] = make_float4(h[4], h[5], h[6], h[7]);
  qp[2] = make_float4(h[8], h[9], h[10], h[11]);
  qp[3] = make_float4(h[12], h[13], h[14], h[15]);
}

// general fallback (bf16 dtype or non-structured Alog) — early-exits when fast ran
template<typename T>
__device__ void scan1_body(const u16* xcLD, const u16* xcTLD, const u16* dtsg, const u32* BCg,
                           const T* Alog, const T* dtw, const T* dtb,
                           float* Sb, float* Qb, float* sdt, float* sB, int fastA){
  int tid = threadIdx.x, blk = blockIdx.x;
  int g = blk & (Gc-1); int k = (blk >> 6) & 3; int b = blk >> 8;
  bool rev = k >= 2, odd = k & 1;
  int d = tid;
  const u16* src = (odd ? xcTLD : xcLD) + (long)b*Ln*Di;
  const u16* dlg = dtsg + (long)(b*Kn + k)*Ln*6;
  const u32* bcg = BCg + (long)(b*Kn + k)*Ln*16;
  float w[6], h[16], a[16];
  #pragma unroll
  for (int r = 0; r < 6; ++r) w[r] = ldv(dtw, ((long)k*Di + d)*6 + r);
  float bias = ldv(dtb, k*Di + d);
  #pragma unroll
  for (int n = 0; n < 16; ++n) h[n] = 0.f;
  if (!fastA){
    #pragma unroll
    for (int n = 0; n < 16; ++n) a[n] = -__expf(ldv(Alog, (long)d*16 + n));
  }
  float S = 0.f;
  int l0 = g*CH;
  for (int i = tid; i < 48; i += 192){
    const u16* sp8 = dlg + (long)l0*6 + i*8;
    ushort4 v0 = *(const ushort4*)sp8;
    ushort4 v1 = *(const ushort4*)(sp8 + 4);
    float* dp = &sdt[i*8];
    dp[0]=bfr(v0.x); dp[1]=bfr(v0.y); dp[2]=bfr(v0.z); dp[3]=bfr(v0.w);
    dp[4]=bfr(v1.x); dp[5]=bfr(v1.y); dp[6]=bfr(v1.z); dp[7]=bfr(v1.w);
  }
  for (int i = tid; i < 256; i += 192){
    uint4 v = *(const uint4*)(bcg + (long)l0*16 + i*4);
    sB[i*4+0] = bfr((u16)(v.x & 0xffff));
    sB[i*4+1] = bfr((u16)(v.y & 0xffff));
    sB[i*4+2] = bfr((u16)(v.z & 0xffff));
    sB[i*4+3] = bfr((u16)(v.w & 0xffff));
  }
  __syncthreads();
  if (fastA){
    for (int jb = 0; jb < CH; jb += 8){
      float uv[8];
      #pragma unroll
      for (int q = 0; q < 8; ++q){
        int l = l0 + jb + q; int pos = rev ? (Ln-1-l) : l;
        uv[q] = bfr(src[(long)pos*Di + d]);
      }
      #pragma unroll
      for (int q = 0; q < 8; ++q){
        int j = jb + q;
        float xv = bias;
        #pragma unroll
        for (int r = 0; r < 6; ++r) xv += w[r]*sdt[j*6 + r];
        float dl, rr; sp_decay(xv, dl, rr);
        float du = dl * uv[q];
        float Bv[16];
        *(float4*)&Bv[0]  = *(const float4*)&sB[j*16];
        *(float4*)&Bv[4]  = *(const float4*)&sB[j*16+4];
        *(float4*)&Bv[8]  = *(const float4*)&sB[j*16+8];
        *(float4*)&Bv[12] = *(const float4*)&sB[j*16+12];
        float r2 = rr*rr, r3 = r2*rr, r4 = r2*r2, r8 = r4*r4, r12 = r8*r4;
        float S4[4] = {rr, r2, r3, r4};
        float B4[4] = {1.f, r4, r8, r12};
        #pragma unroll
        for (int n = 0; n < 16; ++n)
          h[n] = (B4[n>>2]*S4[n&3])*h[n] + du*Bv[n];
        S += dl;
      }
    }
  } else {
    for (int jb = 0; jb < CH; jb += 8){
      float uv[8];
      #pragma unroll
      for (int q = 0; q < 8; ++q){
        int l = l0 + jb + q; int pos = rev ? (Ln-1-l) : l;
        uv[q] = bfr(src[(long)pos*Di + d]);
      }
      #pragma unroll
      for (int q = 0; q < 8; ++q){
        int j = jb + q;
        float dl = bias;
        #pragma unroll
        for (int r = 0; r < 6; ++r) dl += w[r]*sdt[j*6 + r];
        dl = splus(dl);
        float du = dl * uv[q];
        float Bv[16];
        *(float4*)&Bv[0]  = *(const float4*)&sB[j*16];
        *(float4*)&Bv[4]  = *(const float4*)&sB[j*16+4];
        *(float4*)&Bv[8]  = *(const float4*)&sB[j*16+8];
        *(float4*)&Bv[12] = *(const float4*)&sB[j*16+12];
        #pragma unroll
        for (int n = 0; n < 16; ++n) h[n] = __expf(dl*a[n])*h[n] + du*Bv[n];
        S += dl;
      }
    }
  }
  long ci = (long)(b*Kn + k)*Gc + g;
  Sb[ci*Di + d] = S;
  float4* qp = (float4*)(Qb + ci*3072 + (long)d*16);
  qp[0] = make_float4(h[0], h[1], h[2], h[3]);
  qp[1] = make_float4(h[4], h[5], h[6], h[7]);
  qp[2] = make_float4(h[8], h[9], h[10], h[11]);
  qp[3] = make_float4(h[12], h[13], h[14], h[15]);
}
__global__ __launch_bounds__(192,3) void k_scan1_gen(const u16* xcLD, const u16* xcTLD, const u16* dtsg,
                                                     const u32* BCg, const void* Alog, const void* dtw,
                                                     const void* dtb, float* Sb, float* Qb,
                                                     const int* flag, const int* flag2){
  __shared__ float sdt[384];
  __shared__ float sB[1024];
  int f = *flag, f2 = *flag2;
  if (f && f2) return;                   // fast kernel handled it
  if (f) scan1_body<float>(xcLD, xcTLD, dtsg, BCg, (const float*)Alog, (const float*)dtw,
                           (const float*)dtb, Sb, Qb, sdt, sB, f2);
  else   scan1_body<bf16 >(xcLD, xcTLD, dtsg, BCg, (const bf16* )Alog, (const bf16* )dtw,
                           (const bf16* )dtb, Sb, Qb, sdt, sB, f2);
}

// ---------------------- cross-chunk fixup: Hin[g] = scan of (exp(a*S), Q) over g
template<typename T>
__device__ void fix_body(const float* Sb, const float* Qb, const T* Alog, float* Hin){
  int bk = blockIdx.x >> 2, qr = blockIdx.x & 3;
  int s0 = qr*768 + threadIdx.x;
  float aa[3], hh[3];
  #pragma unroll
  for (int q = 0; q < 3; ++q){
    int s = s0 + 256*q;
    aa[q] = -__expf(ldv(Alog, s));
    hh[q] = 0.f;
  }
  for (int g = 0; g < Gc; ++g){
    long ci = (long)bk*Gc + g;
    #pragma unroll
    for (int q = 0; q < 3; ++q){
      int s = s0 + 256*q;
      Hin[ci*3072 + s] = hh[q];
      hh[q] = __expf(aa[q]*Sb[ci*Di + (s >> 4)])*hh[q] + Qb[ci*3072 + s];
    }
  }
}
__global__ __launch_bounds__(256) void k_fix(const float* Sb, const float* Qb, const void* Alog,
                                             float* Hin, const int* flag){
  if (*flag) fix_body<float>(Sb, Qb, (const float*)Alog, Hin);
  else       fix_body<bf16 >(Sb, Qb, (const bf16* )Alog, Hin);
}

// ======================= SCAN PASS 2 =======================
__global__ __launch_bounds__(192,3) void k_scan2_fast(const u16* xcLD, const u16* xcTLD,
                                                      const u16* dtsg, const u32* BCg,
                                                      const void* dtw, const void* dtb,
                                                      const float* Hin, u16* ys,
                                                      const int* flag, const int* flag2){
  if (!(*flag && *flag2)) return;
  __shared__ float sdt[384];
  __shared__ float sB[1024];
  __shared__ float sC[1024];
  const float* dtwf = (const float*)dtw;
  const float* dtbf = (const float*)dtb;
  int tid = threadIdx.x, blk = blockIdx.x;
  int g = blk & (Gc-1); int k = (blk >> 6) & 3; int b = blk >> 8;
  bool rev = k >= 2, odd = k & 1;
  int d = tid;
  const u16* src = (odd ? xcTLD : xcLD) + (long)b*Ln*Di;
  const u16* dlg = dtsg + (long)(b*Kn + k)*Ln*6;
  const u32* bcg = BCg + (long)(b*Kn + k)*Ln*16;
  u16* yb = ys + (long)(b*Kn + k)*Ln*Di;
  float w[6], h[16];
  #pragma unroll
  for (int r = 0; r < 6; ++r) w[r] = dtwf[((long)k*Di + d)*6 + r];
  float bias = dtbf[k*Di + d];
  long ci = (long)(b*Kn + k)*Gc + g;
  {
    const float4* hp = (const float4*)(Hin + ci*3072 + (long)d*16);
    float4 h0 = hp[0], h1 = hp[1], h2 = hp[2], h3 = hp[3];
    h[0]=h0.x; h[1]=h0.y; h[2]=h0.z; h[3]=h0.w;
    h[4]=h1.x; h[5]=h1.y; h[6]=h1.z; h[7]=h1.w;
    h[8]=h2.x; h[9]=h2.y; h[10]=h2.z; h[11]=h2.w;
    h[12]=h3.x; h[13]=h3.y; h[14]=h3.z; h[15]=h3.w;
  }
  int l0 = g*CH;
  for (int i = tid; i < 48; i += 192){
    const u16* sp8 = dlg + (long)l0*6 + i*8;
    ushort4 v0 = *(const ushort4*)sp8;
    ushort4 v1 = *(const ushort4*)(sp8 + 4);
    float* dp = &sdt[i*8];
    dp[0]=bfr(v0.x); dp[1]=bfr(v0.y); dp[2]=bfr(v0.z); dp[3]=bfr(v0.w);
    dp[4]=bfr(v1.x); dp[5]=bfr(v1.y); dp[6]=bfr(v1.z); dp[7]=bfr(v1.w);
  }
  for (int i = tid; i < 256; i += 192){
    uint4 v = *(const uint4*)(bcg + (long)l0*16 + i*4);
    sB[i*4+0] = bfr((u16)(v.x & 0xffff)); sC[i*4+0] = bfr((u16)(v.x >> 16));
    sB[i*4+1] = bfr((u16)(v.y & 0xffff)); sC[i*4+1] = bfr((u16)(v.y >> 16));
    sB[i*4+2] = bfr((u16)(v.z & 0xffff)); sC[i*4+2] = bfr((u16)(v.z >> 16));
    sB[i*4+3] = bfr((u16)(v.w & 0xffff)); sC[i*4+3] = bfr((u16)(v.w >> 16));
  }
  __syncthreads();
  for (int jb = 0; jb < CH; jb += 8){
    float uv[8];
    #pragma unroll
    for (int q = 0; q < 8; ++q){
      int l = l0 + jb + q; int pos = rev ? (Ln-1-l) : l;
      uv[q] = bfr(src[(long)pos*Di + d]);
    }
    #pragma unroll
    for (int q = 0; q < 8; ++q){
      int j = jb + q;
      float xv = bias;
      #pragma unroll
      for (int r = 0; r < 6; ++r) xv += w[r]*sdt[j*6 + r];
      float dl, rr; sp_decay(xv, dl, rr);
      float du = dl * uv[q];
      float Bv[16], Cv[16];
      *(float4*)&Bv[0]  = *(const float4*)&sB[j*16];
      *(float4*)&Bv[4]  = *(const float4*)&sB[j*16+4];
      *(float4*)&Bv[8]  = *(const float4*)&sB[j*16+8];
      *(float4*)&Bv[12] = *(const float4*)&sB[j*16+12];
      *(float4*)&Cv[0]  = *(const float4*)&sC[j*16];
      *(float4*)&Cv[4]  = *(const float4*)&sC[j*16+4];
      *(float4*)&Cv[8]  = *(const float4*)&sC[j*16+8];
      *(float4*)&Cv[12] = *(const float4*)&sC[j*16+12];
      float r2 = rr*rr, r3 = r2*rr, r4 = r2*r2, r8 = r4*r4, r12 = r8*r4;
      float S4[4] = {rr, r2, r3, r4};
      float B4[4] = {1.f, r4, r8, r12};
      float y = 0.f;
      #pragma unroll
      for (int n = 0; n < 16; ++n){
        h[n] = (B4[n>>2]*S4[n&3])*h[n] + du*Bv[n];
        y += h[n]*Cv[n];
      }
      int l = l0 + j; int le = rev ? (Ln-1-l) : l;
      int sp = odd ? ((le & 63)*64 + (le >> 6)) : le;
      yb[(long)sp*Di + d] = fbr(y);
    }
  }
}

template<typename T>
__device__ void scan2_body(const u16* xcLD, const u16* xcTLD, const u16* dtsg, const u32* BCg,
                           const T* Alog, const T* dtw, const T* dtb, const float* Hin,
                           u16* ys, float* sdt, float* sB, float* sC, int fastA){
  int tid = threadIdx.x, blk = blockIdx.x;
  int g = blk & (Gc-1); int k = (blk >> 6) & 3; int b = blk >> 8;
  bool rev = k >= 2, odd = k & 1;
  int d = tid;
  const u16* src = (odd ? xcTLD : xcLD) + (long)b*Ln*Di;
  const u16* dlg = dtsg + (long)(b*Kn + k)*Ln*6;
  const u32* bcg = BCg + (long)(b*Kn + k)*Ln*16;
  u16* yb = ys + (long)(b*Kn + k)*Ln*Di;
  float w[6], h[16], a[16];
  #pragma unroll
  for (int r = 0; r < 6; ++r) w[r] = ldv(dtw, ((long)k*Di + d)*6 + r);
  float bias = ldv(dtb, k*Di + d);
  long ci = (long)(b*Kn + k)*Gc + g;
  {
    const float4* hp = (const float4*)(Hin + ci*3072 + (long)d*16);
    float4 h0 = hp[0], h1 = hp[1], h2 = hp[2], h3 = hp[3];
    h[0]=h0.x; h[1]=h0.y; h[2]=h0.z; h[3]=h0.w;
    h[4]=h1.x; h[5]=h1.y; h[6]=h1.z; h[7]=h1.w;
    h[8]=h2.x; h[9]=h2.y; h[10]=h2.z; h[11]=h2.w;
    h[12]=h3.x; h[13]=h3.y; h[14]=h3.z; h[15]=h3.w;
  }
  if (!fastA){
    #pragma unroll
    for (int n = 0; n < 16; ++n) a[n] = -__expf(ldv(Alog, (long)d*16 + n));
  }
  int l0 = g*CH;
  for (int i = tid; i < 48; i += 192){
    const u16* sp8 = dlg + (long)l0*6 + i*8;
    ushort4 v0 = *(const ushort4*)sp8;
    ushort4 v1 = *(const ushort4*)(sp8 + 4);
    float* dp = &sdt[i*8];
    dp[0]=bfr(v0.x); dp[1]=bfr(v0.y); dp[2]=bfr(v0.z); dp[3]=bfr(v0.w);
    dp[4]=bfr(v1.x); dp[5]=bfr(v1.y); dp[6]=bfr(v1.z); dp[7]=bfr(v1.w);
  }
  for (int i = tid; i < 256; i += 192){
    uint4 v = *(const uint4*)(bcg + (long)l0*16 + i*4);
    sB[i*4+0] = bfr((u16)(v.x & 0xffff)); sC[i*4+0] = bfr((u16)(v.x >> 16));
    sB[i*4+1] = bfr((u16)(v.y & 0xffff)); sC[i*4+1] = bfr((u16)(v.y >> 16));
    sB[i*4+2] = bfr((u16)(v.z & 0xffff)); sC[i*4+2] = bfr((u16)(v.z >> 16));
    sB[i*4+3] = bfr((u16)(v.w & 0xffff)); sC[i*4+3] = bfr((u16)(v.w >> 16));
  }
  __syncthreads();
  if (fastA){
    for (int jb = 0; jb < CH; jb += 8){
      float uv[8];
      #pragma unroll
      for (int q = 0; q < 8; ++q){
        int l = l0 + jb + q; int pos = rev ? (Ln-1-l) : l;
        uv[q] = bfr(src[(long)pos*Di + d]);
      }
      #pragma unroll
      for (int q = 0; q < 8; ++q){
        int j = jb + q;
        float xv = bias;
        #pragma unroll
        for (int r = 0; r < 6; ++r) xv += w[r]*sdt[j*6 + r];
        float dl, rr; sp_decay(xv, dl, rr);
        float du = dl * uv[q];
        float Bv[16], Cv[16];
        *(float4*)&Bv[0]  = *(const float4*)&sB[j*16];
        *(float4*)&Bv[4]  = *(const float4*)&sB[j*16+4];
        *(float4*)&Bv[8]  = *(const float4*)&sB[j*16+8];
        *(float4*)&Bv[12] = *(const float4*)&sB[j*16+12];
        *(float4*)&Cv[0]  = *(const float4*)&sC[j*16];
        *(float4*)&Cv[4]  = *(const float4*)&sC[j*16+4];
        *(float4*)&Cv[8]  = *(const float4*)&sC[j*16+8];
        *(float4*)&Cv[12] = *(const float4*)&sC[j*16+12];
        float r2 = rr*rr, r3 = r2*rr, r4 = r2*r2, r8 = r4*r4, r12 = r8*r4;
        float S4[4] = {rr, r2, r3, r4};
        float B4[4] = {1.f, r4, r8, r12};
        float y = 0.f;
        #pragma unroll
        for (int n = 0; n < 16; ++n){
          h[n] = (B4[n>>2]*S4[n&3])*h[n] + du*Bv[n];
          y += h[n]*Cv[n];
        }
        int l = l0 + j; int le = rev ? (Ln-1-l) : l;
        int sp = odd ? ((le & 63)*64 + (le >> 6)) : le;
        yb[(long)sp*Di + d] = fbr(y);
      }
    }
  } else {
    for (int jb = 0; jb < CH; jb += 8){
      float uv[8];
      #pragma unroll
      for (int q = 0; q < 8; ++q){
        int l = l0 + jb + q; int pos = rev ? (Ln-1-l) : l;
        uv[q] = bfr(src[(long)pos*Di + d]);
      }
      #pragma unroll
      for (int q = 0; q < 8; ++q){
        int j = jb + q;
        float dl = bias;
        #pragma unroll
        for (int r = 0; r < 6; ++r) dl += w[r]*sdt[j*6 + r];
        dl = splus(dl);
        float du = dl * uv[q];
        float Bv[16], Cv[16];
        *(float4*)&Bv[0]  = *(const float4*)&sB[j*16];
        *(float4*)&Bv[4]  = *(const float4*)&sB[j*16+4];
        *(float4*)&Bv[8]  = *(const float4*)&sB[j*16+8];
        *(float4*)&Bv[12] = *(const float4*)&sB[j*16+12];
        *(float4*)&Cv[0]  = *(const float4*)&sC[j*16];
        *(float4*)&Cv[4]  = *(const float4*)&sC[j*16+4];
        *(float4*)&Cv[8]  = *(const float4*)&sC[j*16+8];
        *(float4*)&Cv[12] = *(const float4*)&sC[j*16+12];
        float y = 0.f;
        #pragma unroll
        for (int n = 0; n < 16; ++n){
          h[n] = __expf(dl*a[n])*h[n] + du*Bv[n];
          y += h[n]*Cv[n];
        }
        int l = l0 + j; int le = rev ? (Ln-1-l) : l;
        int sp = odd ? ((le & 63)*64 + (le >> 6)) : le;
        yb[(long)sp*Di + d] = fbr(y);
      }
    }
  }
}
__global__ __launch_bounds__(192,3) void k_scan2_gen(const u16* xcLD, const u16* xcTLD, const u16* dtsg,
                                                     const u32* BCg, const void* Alog, const void* dtw,
                                                     const void* dtb, const float* Hin, u16* ys,
                                                     const int* flag, const int* flag2){
  __shared__ float sdt[384];
  __shared__ float sB[1024];
  __shared__ float sC[1024];
  int f = *flag, f2 = *flag2;
  if (f && f2) return;                   // fast kernel handled it
  if (f) scan2_body<float>(xcLD, xcTLD, dtsg, BCg, (const float*)Alog, (const float*)dtw,
                           (const float*)dtb, Hin, ys, sdt, sB, sC, f2);
  else   scan2_body<bf16 >(xcLD, xcTLD, dtsg, BCg, (const bf16* )Alog, (const bf16* )dtw,
                           (const bf16* )dtb, Hin, ys, sdt, sB, sC, f2);
}

// ------- merge + skip + LayerNorm + gate + out_proj (MFMA, 32 positions/block)
template<typename T>
__device__ void out_body(const u16* ys, const u16* xcLD, const u16* Z, const T* Dsv,
                         const T* lnw, const T* lnb, const T* wo, T* out, long obase,
                         u16* ty, float* sDs){
  int blk = blockIdx.x;
  int b = blk >> 7; int rem = blk & 127; int h = rem >> 1; int half = rem & 1;
  int tid = threadIdx.x;
  int p0 = h*64 + half*32;
  const u16* xcb = xcLD + (long)b*Ln*Di;
  const u16* Zb  = Z + (long)b*Ln*Di;
  const u16* pl0 = ys + (long)(b*Kn + 0)*Ln*Di;
  const u16* pl1 = ys + (long)(b*Kn + 1)*Ln*Di;
  const u16* pl2 = ys + (long)(b*Kn + 2)*Ln*Di;
  const u16* pl3 = ys + (long)(b*Kn + 3)*Ln*Di;
  if (tid < Di)
    sDs[tid] = ldv(Dsv, tid) + ldv(Dsv, Di+tid) + ldv(Dsv, 2*Di+tid) + ldv(Dsv, 3*Di+tid);
  __syncthreads();
  for (int i = tid; i < 768; i += 256){
    int j = i / 24, c8 = (i % 24) * 8;
    int wc = half*32 + j;
    long ls = (long)(p0 + j)*Di + c8;
    long lt = (long)(wc*64 + h)*Di + c8;
    ushort4 a0 = *(const ushort4*)(pl0 + ls); ushort4 a1 = *(const ushort4*)(pl0 + ls + 4);
    ushort4 b0 = *(const ushort4*)(pl2 + ls); ushort4 b1 = *(const ushort4*)(pl2 + ls + 4);
    ushort4 c0 = *(const ushort4*)(pl1 + lt); ushort4 c1 = *(const ushort4*)(pl1 + lt + 4);
    ushort4 d0 = *(const ushort4*)(pl3 + lt); ushort4 d1 = *(const ushort4*)(pl3 + lt + 4);
    ushort4 x0 = *(const ushort4*)(xcb + ls); ushort4 x1 = *(const ushort4*)(xcb + ls + 4);
    u16* tp = &ty[j*200 + c8];
    tp[0] = fbr(bfr(a0.x)+bfr(b0.x)+bfr(c0.x)+bfr(d0.x) + sDs[c8+0]*bfr(x0.x));
    tp[1] = fbr(bfr(a0.y)+bfr(b0.y)+bfr(c0.y)+bfr(d0.y) + sDs[c8+1]*bfr(x0.y));
    tp[2] = fbr(bfr(a0.z)+bfr(b0.z)+bfr(c0.z)+bfr(d0.z) + sDs[c8+2]*bfr(x0.z));
    tp[3] = fbr(bfr(a0.w)+bfr(b0.w)+bfr(c0.w)+bfr(d0.w) + sDs[c8+3]*bfr(x0.w));
    tp[4] = fbr(bfr(a1.x)+bfr(b1.x)+bfr(c1.x)+bfr(d1.x) + sDs[c8+4]*bfr(x1.x));
    tp[5] = fbr(bfr(a1.y)+bfr(b1.y)+bfr(c1.y)+bfr(d1.y) + sDs[c8+5]*bfr(x1.y));
    tp[6] = fbr(bfr(a1.z)+bfr(b1.z)+bfr(c1.z)+bfr(d1.z) + sDs[c8+6]*bfr(x1.z));
    tp[7] = fbr(bfr(a1.w)+bfr(b1.w)+bfr(c1.w)+bfr(d1.w) + sDs[c8+7]*bfr(x1.w));
  }
  __syncthreads();
  int jj = tid >> 3, part = tid & 7;
  float s = 0.f, s2 = 0.f;
  for (int cix = part*24; cix < part*24 + 24; ++cix){
    float v = bfr(ty[jj*200 + cix]); s += v; s2 += v*v;
  }
  s += __shfl_xor(s, 1); s2 += __shfl_xor(s2, 1);
  s += __shfl_xor(s, 2); s2 += __shfl_xor(s2, 2);
  s += __shfl_xor(s, 4); s2 += __shfl_xor(s2, 4);
  float mu = s * (1.f/192.f);
  float var = s2 * (1.f/192.f) - mu*mu;
  float rstd = rsqrtf(fmaxf(var, 0.f) + 1e-5f);
  long zbase = (long)(p0 + jj)*Di;
  for (int cix = part*24; cix < part*24 + 24; ++cix){
    float zv = bfr(Zb[zbase + cix]);
    float gt = zv / (1.f + __expf(-zv));
    float yn = (bfr(ty[jj*200 + cix]) - mu) * rstd * ldv(lnw, cix) + ldv(lnb, cix);
    ty[jj*200 + cix] = fbr(yn * gt);
  }
  __syncthreads();
  int wid = tid >> 6, lane = tid & 63;
  int wm = wid & 1, wn = wid >> 1;
  int lr = lane & 15, lh = lane >> 4;
  f32x4 acc[3] = {};
  #pragma unroll
  for (int ks = 0; ks < 6; ++ks){
    int k0 = ks*32 + lh*8;
    bf16x8 av = *(const bf16x8*)&ty[(wm*16 + lr)*200 + k0];
    #pragma unroll
    for (int n = 0; n < 3; ++n){
      bf16x8 b8 = ldb8(wo + (long)(wn*48 + n*16 + lr)*192 + k0);
      acc[n] = __builtin_amdgcn_mfma_f32_16x16x32_bf16(av, b8, acc[n], 0, 0, 0);
    }
  }
  #pragma unroll
  for (int n = 0; n < 3; ++n){
    int col = wn*48 + n*16 + lr;
    #pragma unroll
    for (int r = 0; r < 4; ++r){
      long row = (long)b*Ln + p0 + wm*16 + lh*4 + r;
      stv(out, obase + row*Cm + col, acc[n][r]);
    }
  }
}
__global__ __launch_bounds__(256) void k_out(const u16* ys, const u16* xcLD, const u16* Z,
                                             const void* Dsv, const void* lnw, const void* lnb,
                                             const void* wo, void* out, long obase, const int* flag){
  __shared__ u16 ty[32*200];
  __shared__ float sDs[Di];
  if (*flag) out_body<float>(ys, xcLD, Z, (const float*)Dsv, (const float*)lnw, (const float*)lnb,
                             (const float*)wo, (float*)out, obase, ty, sDs);
  else       out_body<bf16 >(ys, xcLD, Z, (const bf16* )Dsv, (const bf16* )lnw, (const bf16* )lnb,
                             (const bf16* )wo, (bf16* )out, obase, ty, sDs);
}

extern "C" void kernel_launch(void* const* d_in, const int* in_sizes, int n_in,
                              void* d_out, int out_size, void* d_ws, size_t ws_size,
                              hipStream_t stream){
  const void* x    = d_in[0];
  const void* ipw  = d_in[1];
  const void* cw   = d_in[2];
  const void* cb   = d_in[3];
  const void* xpw  = d_in[4];
  const void* dtw  = d_in[5];
  const void* dtb  = d_in[6];
  const void* Alog = d_in[7];
  const void* Dsv  = d_in[8];
  const void* lnw  = d_in[9];
  const void* lnb  = d_in[10];
  const void* wo   = d_in[11];

  const size_t PLANE = (size_t)Ln*Di*2;
  const size_t YSB   = (size_t)Kn*Ln*Di*2;
  const size_t SBB   = (size_t)Kn*Gc*Di*4;
  const size_t QBB   = (size_t)Kn*Gc*Di*Ns*4;
  const size_t HIB   = QBB;
  const size_t perB  = 4*PLANE + YSB + SBB + QBB + HIB;
  int Bc = 1;
  for (int c : {8, 4, 2, 1}) if (256 + (size_t)c*perB <= ws_size){ Bc = c; break; }
  int nch = 8 / Bc;

  char* base = (char*)d_ws;
  int*  flag  = (int*)base;
  int*  flag2 = (int*)(base + 8);
  u16* Z     = (u16*)(base + 256);
  u16* xcLD  = Z     + (size_t)Bc*Ln*Di;
  u16* xcTLD = xcLD  + (size_t)Bc*Ln*Di;
  u16* Xb    = xcTLD + (size_t)Bc*Ln*Di;
  u16* ys    = Xb    + (size_t)Bc*Ln*Di;
  float* Sb  = (float*)(ys + (size_t)Bc*Kn*Ln*Di);
  float* Qb  = Sb + (size_t)Bc*Kn*Gc*Di;
  float* Hin = Qb + (size_t)Bc*Kn*Gc*Di*Ns;
  u16* dts   = Xb;
  u32* BC    = (u32*)(dts + (size_t)Bc*Kn*Ln*6);

  k_detect<<<1, 256, 0, stream>>>((const u16*)x, Alog, flag, flag2);

  for (int ch = 0; ch < nch; ++ch){
    long xoff = (long)ch*Bc*Ln*Cm;
    k_inproj <<<Bc*Ln/64,     256, 0, stream>>>(x, xoff, ipw, Xb, Z, flag);
    k_conv   <<<Bc*Hn*3,      256, 0, stream>>>(Xb, cw, cb, xcLD, xcTLD, flag);
    k_proj   <<<Bc*(Ln/64)*2, 256, 0, stream>>>(xcLD, xcTLD, xpw, dts, BC, flag);
    k_scan1_fast<<<Bc*Kn*Gc,  192, 0, stream>>>(xcLD, xcTLD, dts, BC, dtw, dtb, Sb, Qb, flag, flag2);
    k_scan1_gen <<<Bc*Kn*Gc,  192, 0, stream>>>(xcLD, xcTLD, dts, BC, Alog, dtw, dtb, Sb, Qb, flag, flag2);
    k_fix    <<<Bc*Kn*4,      256, 0, stream>>>(Sb, Qb, Alog, Hin, flag);
    k_scan2_fast<<<Bc*Kn*Gc,  192, 0, stream>>>(xcLD, xcTLD, dts, BC, dtw, dtb, Hin, ys, flag, flag2);
    k_scan2_gen <<<Bc*Kn*Gc,  192, 0, stream>>>(xcLD, xcTLD, dts, BC, Alog, dtw, dtb, Hin, ys, flag, flag2);
    k_out    <<<Bc*Hn*2,      256, 0, stream>>>(ys, xcLD, Z, Dsv, lnw, lnb, wo, d_out, xoff, flag);
  }
}